// Round 13
// baseline (176.825 us; speedup 1.0000x reference)
//
#include <hip/hip_runtime.h>
#include <hip/hip_fp16.h>

#define TT 512
#define BB 4096
#define CT 8            // timesteps per chunk
#define NCH (TT / CT)   // 64 chunks

__device__ __forceinline__ const float* sel4(int g, const float* a, const float* b,
                                             const float* c, const float* d) {
    return g == 0 ? a : (g == 1 ? b : (g == 2 ? c : d));
}

template<int CTRL>
__device__ __forceinline__ float dppf(float v) {
    int i = __builtin_amdgcn_mov_dpp(__float_as_int(v), CTRL, 0xf, 0xf, true);
    return __int_as_float(i);
}
#define QP(a,b,c,d) ((a) | ((b) << 2) | ((c) << 4) | ((d) << 6))

// ds_swizzle bit-mode: lane' = ((lane & and) | or); and=0x13 keeps {w bits, row bit4},
// or=G<<2 selects gate quad G (exact, direction-free). Proven in r12.
template<int OFS>
__device__ __forceinline__ float swzf(float v) {
    return __int_as_float(__builtin_amdgcn_ds_swizzle(__float_as_int(v), OFS));
}

// direct global->LDS, 16B per lane; LDS dest = uniform base + lane*16
__device__ __forceinline__ void gll16(const void* g, void* l) {
    __builtin_amdgcn_global_load_lds(
        (const __attribute__((address_space(1))) void*)g,
        (__attribute__((address_space(3))) void*)l, 16, 0, 0);
}

// Fully fused, barrier-free QLSTM:
//  - 256 blocks x 256 threads; thread (r=tid>>4, c=tid&15) owns batch row rbase+r, col c.
//  - Ax handoff is THREAD-LOCAL (produced into regs, consumed by same thread's scan).
//  - x staging is WAVE-LOCAL: wave W stages rows 4W..4W+3 for 8 t (16KB/block/chunk,
//    double-buffered) via global_load_lds with lane->(tt,jq,ro) permutation chosen so the
//    produce-phase ds_read_b128 is bank-conflict-free (ro stride = 4 words).
//  - Pipeline: store(ch-1) -> issue loads(ch+1) -> s_waitcnt vmcnt(4) (counted; new loads
//    stay in flight across the whole chunk) -> produce 8 dots -> scan 8 steps.
//  - No __syncthreads, no atomics, no flags; x read once; Ax never touches HBM (and stays
//    fp32 -> absmax improves vs fp16-rounded r12).
__global__ __launch_bounds__(256, 1) void qlstm_fused(
    const float* __restrict__ x,
    const float* __restrict__ Wf, const float* __restrict__ bf, const float* __restrict__ thf,
    const float* __restrict__ Wi, const float* __restrict__ bi, const float* __restrict__ thi,
    const float* __restrict__ Wu, const float* __restrict__ bu, const float* __restrict__ thu,
    const float* __restrict__ Wo, const float* __restrict__ bo, const float* __restrict__ tho,
    float* __restrict__ out)
{
    __shared__ __align__(16) float xs[2][4096];   // 2 x 16KB: [W*1024 + p*256 + tt*128 + jq*16 + ro*4]

    int tid = threadIdx.x;
    int r = tid >> 4, c = tid & 15;     // row-in-block, col L = g*4+w
    int W = r >> 2, ro = r & 3;         // wave, row-in-wave
    int rbase = blockIdx.x * 16;
    int b = rbase + r;
    int w = c & 3, g = c >> 2;

    // ---- produce state: this col's input weights + bias+theta ----
    const float* Wg = sel4(g, Wf, Wi, Wu, Wo);
    float wreg[32];
#pragma unroll
    for (int j = 0; j < 32; ++j) wreg[j] = Wg[j * 4 + w];
    float bth = sel4(g, bf, bi, bu, bo)[w] + sel4(g, thf, thi, thu, tho)[w];

    // ---- scan state (r12, unchanged) ----
    float whA = Wg[(32 + w) * 4 + w];
    float whB = Wg[(32 + (w ^ 1)) * 4 + w];
    float whC = Wg[(32 + (w ^ 2)) * 4 + w];
    float whD = Wg[(32 + (w ^ 3)) * 4 + w];
    bool isU = (g == 2);
    bool wb0 = (w & 1) != 0, wb1 = (w & 2) != 0;
    float d0 = isU ? 0.0f : 0.5f;
    float d1 = isU ? 1.0f : 0.25f;
    float d3 = isU ? -0.33333333f : -0.020833333f;
    float d5 = isU ? 0.13333333f : 0.0020833333f;
    float d7 = isU ? -0.03841007f : -0.000210846f;

    float* outp4 = out + (size_t)b * 4 + c;       // used by c<4 lanes (g=0, w=c)

    // ---- load-lane mapping (independent of (r,c) mapping) ----
    int lane = tid & 63;
    int ltt = lane >> 5, ljq = (lane >> 2) & 7, lro = lane & 3;
    size_t growbase = ((size_t)(rbase + 4 * W + lro)) * 32 + (size_t)ljq * 4;  // + t*BB*32

    float hx = 0.f, cx = 0.f;

    // prologue: stage chunk 0 into buffer 0
#pragma unroll
    for (int p = 0; p < 4; ++p) {
        const float* gp = x + (size_t)(2 * p + ltt) * (BB * 32) + growbase;
        gll16(gp, &xs[0][W * 1024 + p * 256]);
    }

    for (int ch = 0; ch < NCH; ++ch) {
        int t0 = ch * CT;
        int cur = ch & 1;
        if (ch + 1 < NCH) {
#pragma unroll
            for (int p = 0; p < 4; ++p) {
                const float* gp = x + (size_t)(t0 + CT + 2 * p + ltt) * (BB * 32) + growbase;
                gll16(gp, &xs[cur ^ 1][W * 1024 + p * 256]);
            }
            asm volatile("s_waitcnt vmcnt(4)" ::: "memory");   // drain chunk-ch loads + old stores
        } else {
            asm volatile("s_waitcnt vmcnt(0)" ::: "memory");
        }
        __builtin_amdgcn_sched_barrier(0);

        // ---- produce: 8 dot-products (j ascending, same order as r12's pre -> same rounding) ----
        float ax[CT];
#pragma unroll
        for (int t = 0; t < CT; ++t) {
            const float4* row = (const float4*)
                &xs[cur][W * 1024 + (t >> 1) * 256 + (t & 1) * 128 + ro * 4];
            float acc = bth;
#pragma unroll
            for (int jq = 0; jq < 8; ++jq) {
                float4 xv = row[jq * 4];          // 16-float stride -> conflict-free (ro*4 words)
                acc = fmaf(xv.x, wreg[jq * 4 + 0], acc);
                acc = fmaf(xv.y, wreg[jq * 4 + 1], acc);
                acc = fmaf(xv.z, wreg[jq * 4 + 2], acc);
                acc = fmaf(xv.w, wreg[jq * 4 + 3], acc);
            }
            ax[t] = acc;                          // fp32 (no fp16 rounding anymore)
        }

        // ---- scan: 8 steps, r12 step math, ax from registers ----
        float hxs[CT];
#pragma unroll
        for (int k = 0; k < CT; ++k) {
            float axv = ax[k];
            float h1 = dppf<QP(1, 0, 3, 2)>(hx);
            float h2 = dppf<QP(2, 3, 0, 1)>(hx);
            float h3 = dppf<QP(3, 2, 1, 0)>(hx);
            float t1 = fmaf(hx, whA, axv);
            t1 = fmaf(h1, whB, t1);
            float t2 = fmaf(h3, whD, h2 * whC);
            float C = __cosf(t1 + t2);
            float Cx1 = dppf<QP(1, 0, 3, 2)>(C);
            float P   = C * Cx1;
            float Px2 = dppf<QP(2, 3, 0, 1)>(P);
            float Q   = P * Px2;
            float m   = wb1 ? C : Cx1;
            float T   = Px2 * m;
            float z   = wb0 ? (wb1 ? Q : P) : T;
            float z2  = z * z;
            float pp  = fmaf(z2, d7, d5);
            pp = fmaf(z2, pp, d3);
            pp = fmaf(z2, pp, d1);
            float act = fmaf(z, pp, d0);
            float f = swzf<0x0013>(act);
            float i = swzf<0x0093>(act);
            float u = swzf<0x0113>(act);
            float o = swzf<0x0193>(act);
            float c2 = fmaf(f, cx, i * u);
            cx = c2;
            float q2 = c2 * c2;
            float q4 = q2 * q2;
            float dn = fmaf(q2, 420.0f, fmaf(q4, 15.0f, 945.0f));
            float nm = c2 * fmaf(q2, 105.0f, 945.0f + q4);
            hx = o * (nm * __builtin_amdgcn_rcpf(dn));
            hxs[k] = hx;
        }
        if (c < 4) {                              // dedup store: g=0 quad holds w=0..3
#pragma unroll
            for (int k = 0; k < CT; ++k)
                outp4[(size_t)(t0 + k) * 16384] = hxs[k];
        }
    }

    if (c < 4) {
        outp4[(size_t)TT * 16384] = hx;
        outp4[(size_t)TT * 16384 + 16384] = cx;
    }
}

extern "C" void kernel_launch(void* const* d_in, const int* in_sizes, int n_in,
                              void* d_out, int out_size, void* d_ws, size_t ws_size,
                              hipStream_t stream) {
    const float* x   = (const float*)d_in[0];
    const float* Wf  = (const float*)d_in[1];
    const float* bf  = (const float*)d_in[2];
    const float* thf = (const float*)d_in[3];
    const float* Wi  = (const float*)d_in[4];
    const float* bi  = (const float*)d_in[5];
    const float* thi = (const float*)d_in[6];
    const float* Wu  = (const float*)d_in[7];
    const float* bu  = (const float*)d_in[8];
    const float* thu = (const float*)d_in[9];
    const float* Wo  = (const float*)d_in[10];
    const float* bo  = (const float*)d_in[11];
    const float* tho = (const float*)d_in[12];
    float* out = (float*)d_out;

    qlstm_fused<<<BB / 16, 256, 0, stream>>>(
        x, Wf, bf, thf, Wi, bi, thi, Wu, bu, thu, Wo, bo, tho, out);
}